// Round 2
// baseline (234.324 us; speedup 1.0000x reference)
//
#include <hip/hip_runtime.h>
#include <hip/hip_bf16.h>

#define NE   64
#define HDIM 4096
#define NTOK 16384

// ---------------------------------------------------------------------------
// Transpose W [E][H] -> Wt [H][E] so per-k expert weights are contiguous
// (enables wave-uniform s_load_dwordx16 in the GEMM).
// ---------------------------------------------------------------------------
__global__ __launch_bounds__(256) void transpose_w(
    const float* __restrict__ W, float* __restrict__ Wt) {
    const int e = blockIdx.x;                 // 64 blocks, one expert each
    for (int k = threadIdx.x; k < HDIM; k += 256) {
        Wt[(size_t)k * NE + e] = W[(size_t)e * HDIM + k];
    }
}

// ---------------------------------------------------------------------------
// GEMM: lane = token. Each lane accumulates 16 experts for one token.
// x read directly from global (float4 per lane, each byte fetched once).
// W read as wave-uniform scalar loads (SGPRs) from transposed Wt.
// No LDS, no barriers. Grid: (256 token-blocks, KSPLIT k-chunks).
// Partial 0 -> out logits region; partials 1..KSPLIT-1 -> ws.
// ---------------------------------------------------------------------------
template <int KSPLIT>
__global__ __launch_bounds__(256, 4) void gemm_logits(
    const float* __restrict__ x, const float* __restrict__ wt,
    float* __restrict__ part0, float* __restrict__ wspart) {
    constexpr int KPER = HDIM / KSPLIT;
    constexpr int NQ = KPER / 4;

    const int lane = threadIdx.x & 63;
    // wave-uniform wave id -> uniform W pointer -> scalar loads
    const int wid = __builtin_amdgcn_readfirstlane(threadIdx.x >> 6);
    const int e0 = wid * 16;
    const int bt = blockIdx.x;                // 0..255 token block
    const int bk = blockIdx.y;                // 0..KSPLIT-1
    const int t = bt * 64 + lane;

    const float* __restrict__ xr = x + (size_t)t * HDIM + (size_t)bk * KPER;
    const float* __restrict__ wbase = wt + (size_t)bk * KPER * NE + e0;

    float acc[16];
#pragma unroll
    for (int i = 0; i < 16; ++i) acc[i] = 0.f;

#pragma unroll 2
    for (int q = 0; q < NQ; ++q) {
        const float4 xv = *reinterpret_cast<const float4*>(xr + q * 4);
        const float xs[4] = {xv.x, xv.y, xv.z, xv.w};
#pragma unroll
        for (int j = 0; j < 4; ++j) {
            const float* __restrict__ wr = wbase + (size_t)(q * 4 + j) * NE;
            float wv[16];
#pragma unroll
            for (int i = 0; i < 16; ++i) wv[i] = wr[i];   // uniform -> s_load
#pragma unroll
            for (int i = 0; i < 16; ++i)
                acc[i] = fmaf(xs[j], wv[i], acc[i]);
        }
    }

    float* dst = (bk == 0 ? part0 : wspart + (size_t)(bk - 1) * NTOK * NE)
                 + (size_t)t * NE + e0;
#pragma unroll
    for (int i = 0; i < 4; ++i) {
        const float4 v = make_float4(acc[4 * i + 0], acc[4 * i + 1],
                                     acc[4 * i + 2], acc[4 * i + 3]);
        *reinterpret_cast<float4*>(dst + 4 * i) = v;
    }
}

// ---------------------------------------------------------------------------
// Router: thread-per-token. Partial 0 lives in the out-logits region; add
// ws partials, write final logits back, softmax*mask -> scores, top-2,
// 2-way softmax + L1 renorm, indices as floats.
// Out layout: [scores 16384*64][logits 16384*64][weights 16384*2][indices 16384*2]
// ---------------------------------------------------------------------------
__global__ __launch_bounds__(256) void router_kernel(
    const float* __restrict__ wspart, const float* __restrict__ mask,
    float* __restrict__ out, int ksplit) {
    const int t = blockIdx.x * 256 + threadIdx.x;
    if (t >= NTOK) return;

    float l[NE];
    float* lo = out + (size_t)NTOK * NE + (size_t)t * NE;  // logits row (= partial 0)
#pragma unroll
    for (int e4 = 0; e4 < NE / 4; ++e4) {
        const float4 v = *reinterpret_cast<const float4*>(&lo[e4 * 4]);
        l[e4 * 4 + 0] = v.x; l[e4 * 4 + 1] = v.y;
        l[e4 * 4 + 2] = v.z; l[e4 * 4 + 3] = v.w;
    }
    for (int c = 1; c < ksplit; ++c) {
        const float* p = wspart + ((size_t)(c - 1) * NTOK + t) * NE;
#pragma unroll
        for (int e4 = 0; e4 < NE / 4; ++e4) {
            const float4 v = *reinterpret_cast<const float4*>(&p[e4 * 4]);
            l[e4 * 4 + 0] += v.x; l[e4 * 4 + 1] += v.y;
            l[e4 * 4 + 2] += v.z; l[e4 * 4 + 3] += v.w;
        }
    }

    // final logits
#pragma unroll
    for (int e4 = 0; e4 < NE / 4; ++e4) {
        const float4 v = make_float4(l[e4 * 4 + 0], l[e4 * 4 + 1],
                                     l[e4 * 4 + 2], l[e4 * 4 + 3]);
        *reinterpret_cast<float4*>(&lo[e4 * 4]) = v;
    }

    // softmax over 64
    float mx = l[0];
#pragma unroll
    for (int e = 1; e < NE; ++e) mx = fmaxf(mx, l[e]);
    float sc[NE];
    float s = 0.f;
#pragma unroll
    for (int e = 0; e < NE; ++e) {
        const float ev = expf(l[e] - mx);
        sc[e] = ev;
        s += ev;
    }
    const float inv = 1.f / s;
    const float* mrow = mask + (size_t)(t >> 12) * NE;
#pragma unroll
    for (int e = 0; e < NE; ++e) sc[e] = mrow[e] * (sc[e] * inv);

    // scores
    float* so = out + (size_t)t * NE;
#pragma unroll
    for (int e4 = 0; e4 < NE / 4; ++e4) {
        const float4 v = make_float4(sc[e4 * 4 + 0], sc[e4 * 4 + 1],
                                     sc[e4 * 4 + 2], sc[e4 * 4 + 3]);
        *reinterpret_cast<float4*>(&so[e4 * 4]) = v;
    }

    // top-2 (strict > keeps lowest index on ties, matching jax.lax.top_k)
    float v1 = -3.4e38f, v2 = -3.4e38f;
    int i1 = 0, i2 = 0;
#pragma unroll
    for (int e = 0; e < NE; ++e) {
        const float v = sc[e];
        if (v > v1) {
            v2 = v1; i2 = i1;
            v1 = v;  i1 = e;
        } else if (v > v2) {
            v2 = v; i2 = e;
        }
    }

    const float e2v = expf(v2 - v1);
    float w1 = 1.f / (1.f + e2v);
    float w2 = e2v / (1.f + e2v);
    const float sw = w1 + w2;
    w1 /= sw; w2 /= sw;

    const size_t wo = (size_t)2 * NTOK * NE;
    out[wo + (size_t)t * 2 + 0] = w1;
    out[wo + (size_t)t * 2 + 1] = w2;
    const size_t io = wo + (size_t)NTOK * 2;
    out[io + (size_t)t * 2 + 0] = (float)i1;
    out[io + (size_t)t * 2 + 1] = (float)i2;
}

extern "C" void kernel_launch(void* const* d_in, const int* in_sizes, int n_in,
                              void* d_out, int out_size, void* d_ws, size_t ws_size,
                              hipStream_t stream) {
    const float* x    = (const float*)d_in[0];
    const float* mask = (const float*)d_in[1];
    const float* W    = (const float*)d_in[2];
    float* out = (float*)d_out;
    float* ws  = (float*)d_ws;

    const size_t per = (size_t)NTOK * NE * sizeof(float);   // 4 MB per partial
    const size_t wt_bytes = (size_t)HDIM * NE * sizeof(float); // 1 MB

    int ksplit;
    if (ws_size >= 7 * per + wt_bytes)      ksplit = 8;   // 29 MB
    else if (ws_size >= 3 * per + wt_bytes) ksplit = 4;   // 13 MB
    else                                    ksplit = 2;   // 5 MB

    float* wspart = ws;                                       // ksplit-1 partials
    float* wtp    = ws + (size_t)(ksplit - 1) * NTOK * NE;    // transposed W
    float* part0  = out + (size_t)NTOK * NE;                  // logits region

    transpose_w<<<dim3(NE), dim3(256), 0, stream>>>(W, wtp);

    switch (ksplit) {
        case 8: gemm_logits<8><<<dim3(256, 8), dim3(256), 0, stream>>>(x, wtp, part0, wspart); break;
        case 4: gemm_logits<4><<<dim3(256, 4), dim3(256), 0, stream>>>(x, wtp, part0, wspart); break;
        default: gemm_logits<2><<<dim3(256, 2), dim3(256), 0, stream>>>(x, wtp, part0, wspart); break;
    }

    router_kernel<<<dim3(NTOK / 256), dim3(256), 0, stream>>>(wspart, mask, out, ksplit);
}